// Round 4
// baseline (77.174 us; speedup 1.0000x reference)
//
#include <hip/hip_runtime.h>
#include <hip/hip_bf16.h>

// ---- problem constants ----
#define BATCH  65536
#define KREAL  784          // 28*28 = GEMM-K (conv folded into Weff)
#define BK     64
#define NCHUNK 13
#define HID    128
#define NOUT   10
#define BM     64           // rows per block
#define NTHR   256          // 4 waves

using f32x4  = __attribute__((ext_vector_type(4))) float;
using short8 = __attribute__((ext_vector_type(8))) short;   // 8 bf16
using f4     = __attribute__((ext_vector_type(4))) float;

__device__ inline short f2b(float f) {
    union { __hip_bfloat16 h; short s; } u;
    u.h = __float2bfloat16(f);               // hardware RNE cvt
    return u.s;
}

// ---------------------------------------------------------------------------
// Prep:
//  weff_f = conv folded into w1, bf16, FRAGMENT-ORDERED:
//    flat ((((ic*2+kk)*8+t)*4+hi)*16+lo)*8+e  <->  Weff[t*16+lo][ic*64+kk*32+hi*8+e]
//  so each MFMA B-fragment load (fixed ic,kk,t; lanes lo,hi) is a lane-linear,
//  fully-coalesced 1 KB dwordx4 burst (L1-friendly).
//  w2f = w2 fragment-ordered likewise: ((kk*4+hi)*16+lo)*8+e <-> w2[lo][kk*32+hi*8+e]
//  (rows >= 10 zero-padded), kk in [0,4).
// ---------------------------------------------------------------------------
#define NWF (NCHUNK*2*8*4*16*8)   // 106496
#define NW2 (4*4*16*8)            // 2048

__global__ void prep_kernel(const float* __restrict__ conv_w,
                            const float* __restrict__ w1,
                            const float* __restrict__ w2,
                            unsigned short* __restrict__ weff_f,
                            unsigned short* __restrict__ w2f)
{
    int idx = blockIdx.x * 256 + threadIdx.x;
    if (idx < NWF) {
        int e  = idx & 7;
        int lo = (idx >> 3) & 15;
        int hi = (idx >> 7) & 3;
        int t  = (idx >> 9) & 7;
        int kk = (idx >> 12) & 1;
        int ic = idx >> 13;
        int row = t * 16 + lo;                       // output col (0..127)
        int k   = ic * BK + kk * 32 + hi * 8 + e;    // K index
        float acc = 0.f;
        if (k < KREAL) {
            int rr = k / 28, c = k - rr * 28;
            #pragma unroll
            for (int di = 0; di < 3; ++di) {
                int i = rr - di;
                if (i >= 0 && i < 26) {
                    #pragma unroll
                    for (int dj = 0; dj < 3; ++dj) {
                        int j = c - dj;
                        if (j >= 0 && j < 26)
                            acc = fmaf(w1[row * 676 + i * 26 + j], conv_w[di * 3 + dj], acc);
                    }
                }
            }
        }
        weff_f[idx] = (unsigned short)f2b(acc);
    } else {
        int k2 = idx - NWF;
        if (k2 < NW2) {
            int e  = k2 & 7;
            int lo = (k2 >> 3) & 15;
            int hi = (k2 >> 7) & 3;
            int kk = k2 >> 9;
            float v = (lo < NOUT) ? w2[lo * HID + kk * 32 + hi * 8 + e] : 0.f;
            w2f[k2] = (unsigned short)f2b(v);
        }
    }
}

// ---------------------------------------------------------------------------
// Fused: relu(x @ Weff^T + b1) @ w2^T + b2
// ZERO barriers. A: global->reg per lane (own rows). B: fragment-ordered
// global reads, L1/L2-resident (weff = 208 KB). Each wave fully independent.
// LDS only for the per-wave FC2 transpose of h (wave reads its own writes).
// ---------------------------------------------------------------------------
__global__ __launch_bounds__(NTHR, 4)
void fused_mlp_kernel(const float* __restrict__ x,
                      const float* __restrict__ b1,
                      const float* __restrict__ b2,
                      const unsigned short* __restrict__ weff_f,
                      const unsigned short* __restrict__ w2f,
                      float* __restrict__ out)
{
    __shared__ __align__(16) unsigned short ldsH[BM * HID];   // 16 KB, per-wave slices

    const int tid  = threadIdx.x;
    const int wv   = tid >> 6;
    const int lane = tid & 63;
    const int lo   = lane & 15;
    const int hi   = lane >> 4;
    const int row0 = blockIdx.x * BM;
    const int wr0  = wv * 16;

    f32x4 acc[8];
    #pragma unroll
    for (int t = 0; t < 8; ++t) acc[t] = (f32x4){0.f, 0.f, 0.f, 0.f};

    const f4 fz = {0.f, 0.f, 0.f, 0.f};
    const float* arow = x + (long)(row0 + wr0 + lo) * KREAL;   // this lane's A row
    const unsigned short* bfr = weff_f + ((long)hi * 16 + lo) * 8;  // lane's frag base

    #pragma unroll
    for (int ic = 0; ic < NCHUNK; ++ic) {
        const int kbase = ic * BK;
        // A: 16 floats for this chunk (8 per k-substep, contiguous per substep)
        f4 av[4];
        #pragma unroll
        for (int m = 0; m < 4; ++m) {
            int col = kbase + (m >> 1) * 32 + hi * 8 + (m & 1) * 4;
            av[m] = (col < KREAL) ? *(const f4*)(arow + col) : fz;
        }
        short8 af[2];
        #pragma unroll
        for (int kk = 0; kk < 2; ++kk)
            #pragma unroll
            for (int e = 0; e < 4; ++e) {
                af[kk][e]     = f2b(av[kk * 2][e]);
                af[kk][4 + e] = f2b(av[kk * 2 + 1][e]);
            }
        #pragma unroll
        for (int kk = 0; kk < 2; ++kk) {
            const unsigned short* bs = bfr + ((long)(ic * 2 + kk) * 8) * 512;
            #pragma unroll
            for (int t = 0; t < 8; ++t) {
                short8 bfrag = *(const short8*)(bs + (long)t * 512);
                acc[t] = __builtin_amdgcn_mfma_f32_16x16x32_bf16(af[kk], bfrag, acc[t], 0, 0, 0);
            }
        }
    }

    // ---- FC1 epilogue: +b1, ReLU, h -> swizzled per-wave ldsH slice ----
    // C/D layout: col = lane&15, row = (lane>>4)*4 + reg
    #pragma unroll
    for (int t = 0; t < 8; ++t) {
        float bias = b1[t * 16 + lo];
        #pragma unroll
        for (int j = 0; j < 4; ++j) {
            float hv = acc[t][j] + bias;
            hv = hv > 0.f ? hv : 0.f;
            int rloc = wr0 + hi * 4 + j;
            int col  = t * 16 + lo;
            int g    = col >> 3, e = col & 7;
            ldsH[rloc * HID + ((g ^ (rloc & 7)) << 3) + e] = (unsigned short)f2b(hv);
        }
    }
    // wave reads only its own writes -> compiler lgkmcnt suffices, no barrier

    // ---- FC2: h[16x128] @ w2^T[128x16] per wave, 4 MFMAs ----
    f32x4 acc2 = (f32x4){0.f, 0.f, 0.f, 0.f};
    #pragma unroll
    for (int kk = 0; kk < 4; ++kk) {
        int r = wr0 + lo;
        int g = kk * 4 + hi;
        short8 ha = *(const short8*)&ldsH[r * HID + ((g ^ (r & 7)) << 3)];
        short8 wb = *(const short8*)(w2f + (((kk * 4 + hi) * 16 + lo) << 3));
        acc2 = __builtin_amdgcn_mfma_f32_16x16x32_bf16(ha, wb, acc2, 0, 0, 0);
    }
    if (lo < NOUT) {
        float bb = b2[lo];
        #pragma unroll
        for (int j = 0; j < 4; ++j) {
            int grow = row0 + wr0 + hi * 4 + j;
            out[grow * NOUT + lo] = acc2[j] + bb;
        }
    }
}

// ---------------------------------------------------------------------------
extern "C" void kernel_launch(void* const* d_in, const int* in_sizes, int n_in,
                              void* d_out, int out_size, void* d_ws, size_t ws_size,
                              hipStream_t stream)
{
    const float* x      = (const float*)d_in[0];
    const float* conv_w = (const float*)d_in[1];
    const float* w1     = (const float*)d_in[2];
    const float* b1     = (const float*)d_in[3];
    const float* w2     = (const float*)d_in[4];
    const float* b2     = (const float*)d_in[5];
    float* out = (float*)d_out;

    unsigned short* weff_f = (unsigned short*)d_ws;     // 106496 bf16
    unsigned short* w2f    = weff_f + NWF;              // 2048 bf16

    const int prep_total = NWF + NW2;                   // 108544
    prep_kernel<<<(prep_total + 255) / 256, 256, 0, stream>>>(conv_w, w1, w2, weff_f, w2f);
    fused_mlp_kernel<<<BATCH / BM, NTHR, 0, stream>>>(x, b1, b2, weff_f, w2f, out);
}

// Round 5
// 44.044 us; speedup vs baseline: 1.7522x; 1.7522x over previous
//
#include <hip/hip_runtime.h>
#include <hip/hip_bf16.h>

// ---- problem constants ----
#define BATCH  65536
#define KREAL  784          // 28*28 = GEMM-K (conv folded into Weff)
#define BK     64
#define NCHUNK 13
#define HID    128
#define NOUT   10
#define BM     64           // rows per block
#define NTHR   256          // 4 waves

using f32x4  = __attribute__((ext_vector_type(4))) float;
using short8 = __attribute__((ext_vector_type(8))) short;   // 8 bf16
using f4     = __attribute__((ext_vector_type(4))) float;

__device__ inline short f2b(float f) {
    union { __hip_bfloat16 h; short s; } u;
    u.h = __float2bfloat16(f);               // hardware RNE cvt
    return u.s;
}

// global -> LDS direct copy, 16 B per lane. gp: PER-LANE global addr,
// lp: wave-uniform LDS base (HW writes base + lane*16).
#define GLDS16(gp, lp) \
    __builtin_amdgcn_global_load_lds((const __attribute__((address_space(1))) void*)(gp), \
                                     (__attribute__((address_space(3))) void*)(lp), 16, 0, 0)

// ---------------------------------------------------------------------------
// Prep:
//  weff_sw = conv folded into w1, bf16, CHUNK-MAJOR + PRE-SWIZZLED (r2 layout):
//    weff_sw[ic][r][cc] = Weff[r][ic*64 + ((cc>>3)^(r&7))*8 + (cc&7)]
//  w2f = w2 fragment-ordered: ((kk*4+hi)*16+lo)*8+e <-> w2[lo][kk*32+hi*8+e]
// ---------------------------------------------------------------------------
#define NWB (NCHUNK*HID*BK)   // 106496
#define NW2 (4*4*16*8)        // 2048

__global__ void prep_kernel(const float* __restrict__ conv_w,
                            const float* __restrict__ w1,
                            const float* __restrict__ w2,
                            unsigned short* __restrict__ weff_sw,
                            unsigned short* __restrict__ w2f)
{
    int idx = blockIdx.x * 256 + threadIdx.x;
    if (idx < NWB) {
        int ic  = idx >> 13;                 // /(128*64)
        int rem = idx & 8191;
        int r   = rem >> 6;
        int cc  = rem & 63;
        int g   = (cc >> 3) ^ (r & 7);
        int k   = ic * BK + g * 8 + (cc & 7);
        float acc = 0.f;
        if (k < KREAL) {
            int rr = k / 28, c = k - rr * 28;
            #pragma unroll
            for (int di = 0; di < 3; ++di) {
                int i = rr - di;
                if (i >= 0 && i < 26) {
                    #pragma unroll
                    for (int dj = 0; dj < 3; ++dj) {
                        int j = c - dj;
                        if (j >= 0 && j < 26)
                            acc = fmaf(w1[r * 676 + i * 26 + j], conv_w[di * 3 + dj], acc);
                    }
                }
            }
        }
        weff_sw[idx] = (unsigned short)f2b(acc);
    } else {
        int k2 = idx - NWB;
        if (k2 < NW2) {
            int e  = k2 & 7;
            int lo = (k2 >> 3) & 15;
            int hi = (k2 >> 7) & 3;
            int kk = k2 >> 9;
            float v = (lo < NOUT) ? w2[lo * HID + kk * 32 + hi * 8 + e] : 0.f;
            w2f[k2] = (unsigned short)f2b(v);
        }
    }
}

// ---------------------------------------------------------------------------
// Fused: relu(x @ Weff^T + b1) @ w2^T + b2
// A: fp32 staged via global_load_lds with LANE-LINEAR global bursts
//    (4 rows x 256 B contiguous per instruction; source granule pre-swizzled
//    gi^(row&15) so fragment reads are bank-balanced). No staging VALU.
// B: pre-swizzled weff chunk, linear 16 KB global_load_lds (r2, proven).
// Both double-buffered; ONE barrier per chunk (stage ic+1, compute ic).
// ---------------------------------------------------------------------------
__global__ __launch_bounds__(NTHR, 2)
void fused_mlp_kernel(const float* __restrict__ x,
                      const float* __restrict__ b1,
                      const float* __restrict__ b2,
                      const unsigned short* __restrict__ weff_sw,
                      const unsigned short* __restrict__ w2f,
                      float* __restrict__ out)
{
    __shared__ __align__(16) unsigned char smem[65536];      // 64 KB
    float*          bufA0 = (float*)smem;                    // [64][64 fp32] swz
    float*          bufA1 = (float*)(smem + 16384);
    unsigned short* bufB0 = (unsigned short*)(smem + 32768); // [128][64 bf16] swz
    unsigned short* bufB1 = (unsigned short*)(smem + 49152);
    unsigned short* ldsH  = (unsigned short*)smem;           // [64][128] alias

    const int tid  = threadIdx.x;
    const int wv   = tid >> 6;
    const int lane = tid & 63;
    const int lo   = lane & 15;
    const int hi   = lane >> 4;
    const int row0 = blockIdx.x * BM;
    const int wr0  = wv * 16;

    f32x4 acc[8];
    #pragma unroll
    for (int t = 0; t < 8; ++t) acc[t] = (f32x4){0.f, 0.f, 0.f, 0.f};

    // A-stage: wave stages its OWN 16 rows; instr j covers rows wv*16+j*4+hi,
    // lane granule gi=lo swizzled to source granule gi^(row&15).
    const char* abase = (const char*)(x + (long)(row0 + wr0 + hi) * KREAL);
    auto stageA = [&](int ic, float* dst) {
        #pragma unroll
        for (int j = 0; j < 4; ++j) {
            int sg = lo ^ (j * 4 + hi);              // source granule16 in row
            int ce = ic * BK + sg * 4;               // first fp32 col
            int cb = (ce < KREAL) ? ce : 0;          // clamp (chunk 12 only)
            GLDS16(abase + (long)j * 4 * KREAL * 4 + cb * 4,
                   (char*)dst + (wr0 + j * 4) * 256);
        }
    };
    auto stageB = [&](int ic, unsigned short* dst) {
        const char* src = (const char*)(weff_sw + (long)ic * (HID * BK));
        #pragma unroll
        for (int j = 0; j < 4; ++j)
            GLDS16(src + wv * 4096 + j * 1024 + lane * 16,
                   (char*)dst + wv * 4096 + j * 1024);
    };

    // ---- prologue: chunk 0 in flight ----
    stageA(0, bufA0);
    stageB(0, bufB0);

    #pragma unroll
    for (int ic = 0; ic < NCHUNK; ++ic) {
        __syncthreads();   // vmcnt drain: chunk-ic staged; buf^1 free for reuse
        const float*          Ac = (ic & 1) ? bufA1 : bufA0;
        const unsigned short* Bc = (ic & 1) ? bufB1 : bufB0;
        if (ic + 1 < NCHUNK) {
            stageA(ic + 1, (ic & 1) ? bufA0 : bufA1);
            stageB(ic + 1, (ic & 1) ? bufB0 : bufB1);
        }
        const int r = wr0 + lo;                      // this lane's A row
        #pragma unroll
        for (int kk = 0; kk < 2; ++kk) {
            const int G = kk * 4 + hi;               // 32B granule (8 fp32)
            f4 a0 = *(const f4*)((const char*)Ac + r * 256 + ((( 2 * G    ) ^ lo) << 4));
            f4 a1 = *(const f4*)((const char*)Ac + r * 256 + (((2 * G + 1) ^ lo) << 4));
            short8 af;
            #pragma unroll
            for (int e = 0; e < 4; ++e) {
                af[e]     = f2b(a0[e]);
                af[4 + e] = f2b(a1[e]);
            }
            #pragma unroll
            for (int t = 0; t < 8; ++t) {
                const int ob = t * 16 + lo;
                short8 bfrag = *(const short8*)&Bc[ob * BK + ((G ^ (ob & 7)) << 3)];
                acc[t] = __builtin_amdgcn_mfma_f32_16x16x32_bf16(af, bfrag, acc[t], 0, 0, 0);
            }
        }
    }

    __syncthreads();       // all reads done before ldsH alias write

    // ---- FC1 epilogue: +b1, ReLU, h -> swizzled per-wave ldsH slice ----
    // C/D layout: col = lane&15, row = (lane>>4)*4 + reg
    #pragma unroll
    for (int t = 0; t < 8; ++t) {
        float bias = b1[t * 16 + lo];
        #pragma unroll
        for (int j = 0; j < 4; ++j) {
            float hv = acc[t][j] + bias;
            hv = hv > 0.f ? hv : 0.f;
            int rloc = wr0 + hi * 4 + j;
            int col  = t * 16 + lo;
            int g    = col >> 3, e = col & 7;
            ldsH[rloc * HID + ((g ^ (rloc & 7)) << 3) + e] = (unsigned short)f2b(hv);
        }
    }
    // wave reads only its own writes -> compiler lgkmcnt suffices, no barrier

    // ---- FC2: h[16x128] @ w2^T[128x16] per wave, 4 MFMAs ----
    f32x4 acc2 = (f32x4){0.f, 0.f, 0.f, 0.f};
    #pragma unroll
    for (int kk = 0; kk < 4; ++kk) {
        int r = wr0 + lo;
        int g = kk * 4 + hi;
        short8 ha = *(const short8*)&ldsH[r * HID + ((g ^ (r & 7)) << 3)];
        short8 wb = *(const short8*)(w2f + (((kk * 4 + hi) * 16 + lo) << 3));
        acc2 = __builtin_amdgcn_mfma_f32_16x16x32_bf16(ha, wb, acc2, 0, 0, 0);
    }
    if (lo < NOUT) {
        float bb = b2[lo];
        #pragma unroll
        for (int j = 0; j < 4; ++j) {
            int grow = row0 + wr0 + hi * 4 + j;
            out[grow * NOUT + lo] = acc2[j] + bb;
        }
    }
}

// ---------------------------------------------------------------------------
extern "C" void kernel_launch(void* const* d_in, const int* in_sizes, int n_in,
                              void* d_out, int out_size, void* d_ws, size_t ws_size,
                              hipStream_t stream)
{
    const float* x      = (const float*)d_in[0];
    const float* conv_w = (const float*)d_in[1];
    const float* w1     = (const float*)d_in[2];
    const float* b1     = (const float*)d_in[3];
    const float* w2     = (const float*)d_in[4];
    const float* b2     = (const float*)d_in[5];
    float* out = (float*)d_out;

    unsigned short* weff_sw = (unsigned short*)d_ws;    // 106496 bf16
    unsigned short* w2f     = weff_sw + NWB;            // 2048 bf16

    const int prep_total = NWB + NW2;                   // 108544
    prep_kernel<<<(prep_total + 255) / 256, 256, 0, stream>>>(conv_w, w1, w2, weff_sw, w2f);
    fused_mlp_kernel<<<BATCH / BM, NTHR, 0, stream>>>(x, b1, b2, weff_sw, w2f, out);
}